// Round 4
// baseline (1126.536 us; speedup 1.0000x reference)
//
#include <hip/hip_runtime.h>

// SimpleMACELayer on gfx950 — round 4: register-prefetched F + merged phases + sA swizzle.
//
//   F[h][o2][kk]   = sum_o tpw[p(kk)][h][o] * W_lin[o2][o*16 + kg(kk)]  (f16, kk pad 128, ws)
//   CGd[kk][i][j]  = masked-dense Gaunt slice (f16, ws)
//   A_e[kk][i]     = CGd[kk]·Y_e          (MFMA 16x16x16, built during G2(hg=3) phase)
//   U[e][h][kk]    = A_e·src_e            (GEMM-1)
//   out[dst,:]    += U·F                  (GEMM-2, F prefetched into pf[4][4] regs a phase early)
//
// Round-3 post-mortem: all pipes <15%, waves stall on in-phase L2 F-loads (56 VGPR = few
// in flight) between 36 barriers. Fix: 64-VGPR F prefetch one phase ahead; A-build merged
// into G2(hg=3); sA XOR-swizzle kills the 4-way G1 read conflict.

#define NKK 99
#define NKPAD 128
#define EPB 16
#define THREADS 256
#define SA_ESTR 516   // [e][kk32][i16] f16 (+ XOR i-block swizzle)
#define SU_HSTR 40    // [e][h'16][kk32] f16
#define SU_ESTR 648

typedef _Float16 f16;
typedef f16 f16x4 __attribute__((ext_vector_type(4)));
typedef f16 f16x8 __attribute__((ext_vector_type(8)));
typedef float f32x4 __attribute__((ext_vector_type(4)));

__device__ __constant__ short PK_P[NKK] = {
  0, 1,1,1, 2,2,2,2,2, 3,3,3,3,3,3,3, 4,4,4, 5, 6,6,6,6,6, 7,7,7,
  8,8,8,8,8,8,8, 9,9,9,9,9, 10,10,10,10,10, 11,11,11, 12,12,12,12,12,12,12,
  13, 14,14,14,14,14, 15,15,15, 16,16,16,16,16,16,16, 17,17,17,17,17,17,17,
  18,18,18,18,18, 19,19,19, 20,20,20,20,20,20,20, 21, 22,22,22,22,22};
__device__ __constant__ short KK_L1[NKK] = {
  0, 0,0,0, 0,0,0,0,0, 0,0,0,0,0,0,0, 1,1,1, 1, 1,1,1,1,1, 1,1,1,
  1,1,1,1,1,1,1, 1,1,1,1,1, 2,2,2,2,2, 2,2,2, 2,2,2,2,2,2,2,
  2, 2,2,2,2,2, 2,2,2, 2,2,2,2,2,2,2, 3,3,3,3,3,3,3,
  3,3,3,3,3, 3,3,3, 3,3,3,3,3,3,3, 3, 3,3,3,3,3};
__device__ __constant__ short KK_L2[NKK] = {
  0, 1,1,1, 2,2,2,2,2, 3,3,3,3,3,3,3, 0,0,0, 1, 1,1,1,1,1, 2,2,2,
  2,2,2,2,2,2,2, 3,3,3,3,3, 0,0,0,0,0, 1,1,1, 1,1,1,1,1,1,1,
  2, 2,2,2,2,2, 3,3,3, 3,3,3,3,3,3,3, 0,0,0,0,0,0,0,
  1,1,1,1,1, 2,2,2, 2,2,2,2,2,2,2, 3, 3,3,3,3,3};
__device__ __constant__ short KK_KG[NKK] = {
  0, 1,2,3, 4,5,6,7,8, 9,10,11,12,13,14,15, 1,2,3, 0, 4,5,6,7,8, 1,2,3,
  9,10,11,12,13,14,15, 4,5,6,7,8, 4,5,6,7,8, 1,2,3, 9,10,11,12,13,14,15,
  0, 4,5,6,7,8, 1,2,3, 9,10,11,12,13,14,15, 9,10,11,12,13,14,15,
  4,5,6,7,8, 1,2,3, 9,10,11,12,13,14,15, 0, 4,5,6,7,8};

__global__ void zero_ws(uint4* __restrict__ F) {
  F[blockIdx.x * 256 + threadIdx.x] = uint4{0, 0, 0, 0};
}

__global__ __launch_bounds__(256) void compute_F(const float* __restrict__ tpw,
                                                 const float* __restrict__ wlin,
                                                 f16* __restrict__ F) {
  int kk = blockIdx.x;
  int p  = PK_P[kk];
  int c3 = KK_KG[kk];

  __shared__ float wl[64][65];
  int tid = threadIdx.x;
  for (int idx = tid; idx < 64 * 64; idx += 256) {
    int o2 = idx >> 6, o = idx & 63;
    wl[o2][o] = wlin[o2 * 1024 + o * 16 + c3];
  }
  __syncthreads();

  int h = tid & 63, og = tid >> 6;
  float acc[16];
#pragma unroll
  for (int m = 0; m < 16; ++m) acc[m] = 0.f;
  const float* tw = tpw + (p * 64 + h) * 64;
  for (int o = 0; o < 64; ++o) {
    float w = tw[o];
#pragma unroll
    for (int m = 0; m < 16; ++m) acc[m] += w * wl[og * 16 + m][o];
  }
#pragma unroll
  for (int m = 0; m < 16; ++m)
    F[(size_t)(h * 64 + og * 16 + m) * NKPAD + kk] = (f16)acc[m];
}

__global__ void compute_CGd(const float* __restrict__ cg, f16* __restrict__ CGd) {
  int kk = blockIdx.x;
  int i = threadIdx.x >> 4, j = threadIdx.x & 15;
  f16 v = (f16)0.f;
  if (kk < NKK) {
    int l1 = KK_L1[kk], l2 = KK_L2[kk], kg = KK_KG[kk];
    int b1 = l1 * l1, b2 = l2 * l2;
    if (i >= b1 && i < b1 + 2 * l1 + 1 && j >= b2 && j < b2 + 2 * l2 + 1)
      v = (f16)cg[(i * 16 + j) * 16 + kg];
  }
  CGd[kk * 256 + i * 16 + j] = v;
}

__global__ void init_out(float* __restrict__ out, const float* __restrict__ b, int n) {
  int i = blockIdx.x * 256 + threadIdx.x;
  if (i < n) out[i] = b[i & 63];
}

// ---------------- main edge kernel
__global__ __launch_bounds__(THREADS, 4) void edge_kernel(
    const float* __restrict__ nf, const float* __restrict__ ev,
    const int* __restrict__ eidx, const f16* __restrict__ CGd,
    const f16* __restrict__ F, float* __restrict__ out, int NE) {

  __shared__ f16 sYh[EPB * 16];
  __shared__ int sSrcA[EPB];
  __shared__ int sDst[EPB];
  __shared__ f16 sA[EPB * SA_ESTR];   // 16.5KB ; reused as fp32 red
  __shared__ f16 sU[EPB * SU_ESTR];   // 20.7KB

  int tid = threadIdx.x;
  int wave = tid >> 6, lane = tid & 63;
  int lm = lane & 15, lq = lane >> 4;

  // --- phase 0: edge meta + spherical harmonics (f16)
  if (tid < EPB) {
    int eg = blockIdx.x * EPB + tid;
    int sa = 0, da = -1;
    float x = 0.f, y = 0.f, z = 0.f;
    if (eg < NE) {
      sa = eidx[eg];
      da = eidx[NE + eg];
      x = ev[3 * eg + 0]; y = ev[3 * eg + 1]; z = ev[3 * eg + 2];
    }
    sSrcA[tid] = sa;
    sDst[tid] = da;
    float x2 = x * x, y2 = y * y, z2 = z * z;
    float Y[16];
    Y[0]  = 0.28209479177387814f;
    Y[1]  = 0.4886025119029199f * y;
    Y[2]  = 0.4886025119029199f * z;
    Y[3]  = 0.4886025119029199f * x;
    Y[4]  = 1.0925484305920792f * x * y;
    Y[5]  = 1.0925484305920792f * y * z;
    Y[6]  = 0.31539156525252005f * (3.0f * z2 - 1.0f);
    Y[7]  = 1.0925484305920792f * x * z;
    Y[8]  = 0.5462742152960396f * (x2 - y2);
    Y[9]  = 0.5900435899266435f * y * (3.0f * x2 - y2);
    Y[10] = 2.890611442640554f * x * y * z;
    Y[11] = 0.4570457994644658f * y * (5.0f * z2 - 1.0f);
    Y[12] = 0.3731763325901154f * z * (5.0f * z2 - 3.0f);
    Y[13] = 0.4570457994644658f * x * (5.0f * z2 - 1.0f);
    Y[14] = 1.445305721320277f  * z * (x2 - y2);
    Y[15] = 0.5900435899266435f * x * (x2 - 3.0f * y2);
#pragma unroll
    for (int j = 0; j < 16; ++j) sYh[tid * 16 + j] = (f16)Y[j];
  }
  __syncthreads();

  // --- phase 1: Sf gather + bY + A-build(kg=0) + pf(0,0) prefetch
  f16x4 Sf[4][4];
  int ebase = wave * 4;
#pragma unroll
  for (int ei = 0; ei < 4; ++ei) {
    const float4* src4 = (const float4*)nf + (size_t)sSrcA[ebase + ei] * 256;
#pragma unroll
    for (int hg = 0; hg < 4; ++hg) {
      float4 v = src4[(hg * 16 + lm) * 4 + lq];
      Sf[ei][hg] = f16x4{(f16)v.x, (f16)v.y, (f16)v.z, (f16)v.w};
    }
  }

  f16x4 bY = *(const f16x4*)&sYh[lm * 16 + lq * 4];

  // per-lane base offsets
  const f16* Fbase = F + (size_t)lm * NKPAD + lq * 8;     // + h*64*NKPAD + ot*16*NKPAD + kg*32
  int sAw = lm * SA_ESTR;                                 // A-build write base (e = lm)
  int sUw = lm * SU_HSTR;                                 // G1 write h' = lm

  // A-build for kg=0
#pragma unroll
  for (int tl = 0; tl < 8; ++tl) {
    int t = wave * 8 + tl;
    f16x4 aCG = *(const f16x4*)&CGd[(size_t)t * 256 + lm * 16 + lq * 4];
    f32x4 d = __builtin_amdgcn_mfma_f32_16x16x16f16(aCG, bY, f32x4{0.f, 0.f, 0.f, 0.f}, 0, 0, 0);
    f16x4 dh = {(f16)d[0], (f16)d[1], (f16)d[2], (f16)d[3]};
    int loc = lq ^ ((t >> 2) & 3);
    *(f16x4*)&sA[sAw + t * 16 + loc * 4] = dh;
  }

  // prefetch F fragments for phase (kg=0, hg=0)
  f16x8 pf[4][4];
#pragma unroll
  for (int hi = 0; hi < 4; ++hi) {
    int h = wave + 4 * hi;
#pragma unroll
    for (int ot = 0; ot < 4; ++ot)
      pf[hi][ot] = *(const f16x8*)(Fbase + (size_t)(h * 64 + ot * 16) * NKPAD);
  }

  f32x4 acc[4];
#pragma unroll
  for (int ot = 0; ot < 4; ++ot) acc[ot] = f32x4{0.f, 0.f, 0.f, 0.f};

  int swz = (lm >> 2) & 3;   // G1 read swizzle group

  __syncthreads();

  for (int kg = 0; kg < 4; ++kg) {
#pragma unroll
    for (int hg = 0; hg < 4; ++hg) {
      // ---- G1 phase: U[e][h'=lm][kk32] writes
#pragma unroll
      for (int ei = 0; ei < 4; ++ei) {
        int e = ebase + ei;
        f16x4 bS = Sf[ei][hg];
#pragma unroll
        for (int mt = 0; mt < 2; ++mt) {
          f16x4 aA = *(const f16x4*)&sA[e * SA_ESTR + (mt * 16 + lm) * 16 + ((lq ^ swz) << 2)];
          f32x4 d = __builtin_amdgcn_mfma_f32_16x16x16f16(aA, bS, f32x4{0.f, 0.f, 0.f, 0.f}, 0, 0, 0);
          f16x4 dh = {(f16)d[0], (f16)d[1], (f16)d[2], (f16)d[3]};
          *(f16x4*)&sU[e * SU_ESTR + sUw + mt * 16 + lq * 4] = dh;
        }
      }
      __syncthreads();

      // ---- G2 phase: acc += U*F (pf regs, zero load stall); prefetch next phase's F
      int tn = kg * 4 + hg + 1;
      int kgn = (tn >> 2) & 3, hgn = tn & 3;
      const f16* Fn = Fbase + (size_t)(hgn * 16 * 64 + kgn * 16) * NKPAD + kgn * 32 - kgn * 16 * NKPAD;
      // (simplify: recompute cleanly below)
#pragma unroll
      for (int hi = 0; hi < 4; ++hi) {
        int hl = wave + 4 * hi;
        f16x8 a0 = *(const f16x8*)&sU[lm * SU_ESTR + hl * SU_HSTR + lq * 8];
#pragma unroll
        for (int ot = 0; ot < 4; ++ot) {
          acc[ot] = __builtin_amdgcn_mfma_f32_16x16x32_f16(a0, pf[hi][ot], acc[ot], 0, 0, 0);
          int hn = hgn * 16 + wave + 4 * hi;
          pf[hi][ot] = *(const f16x8*)(Fbase + (size_t)(hn * 64 + ot * 16) * NKPAD + kgn * 32);
        }
      }
      (void)Fn;

      if (hg == 3) {
        // A-build for next kg (sA free: last read was G1 of this kg)
        int kga = (kg + 1) & 3;
#pragma unroll
        for (int tl = 0; tl < 8; ++tl) {
          int t = wave * 8 + tl;
          f16x4 aCG = *(const f16x4*)&CGd[(size_t)(kga * 32 + t) * 256 + lm * 16 + lq * 4];
          f32x4 d = __builtin_amdgcn_mfma_f32_16x16x16f16(aCG, bY, f32x4{0.f, 0.f, 0.f, 0.f}, 0, 0, 0);
          f16x4 dh = {(f16)d[0], (f16)d[1], (f16)d[2], (f16)d[3]};
          int loc = lq ^ ((t >> 2) & 3);
          *(f16x4*)&sA[sAw + t * 16 + loc * 4] = dh;
        }
      }
      __syncthreads();
    }
  }

  // --- cross-wave reduction: red[e][o2][wave] + atomic scatter
  float* red = (float*)sA;
#pragma unroll
  for (int ot = 0; ot < 4; ++ot) {
#pragma unroll
    for (int r = 0; r < 4; ++r) {
      int e = lq * 4 + r;
      int o2 = ot * 16 + lm;
      red[(e * 64 + o2) * 4 + wave] = acc[ot][r];
    }
  }
  __syncthreads();

#pragma unroll
  for (int rep = 0; rep < 4; ++rep) {
    int idx = tid + rep * 256;
    float4 v = *(const float4*)&red[idx * 4];
    float s = v.x + v.y + v.z + v.w;
    int e = idx >> 6, o2 = idx & 63;
    int da = sDst[e];
    if (da >= 0) unsafeAtomicAdd(out + (size_t)da * 64 + o2, s);
  }
}

extern "C" void kernel_launch(void* const* d_in, const int* in_sizes, int n_in,
                              void* d_out, int out_size, void* d_ws, size_t ws_size,
                              hipStream_t stream) {
  const float* nf   = (const float*)d_in[0];
  const float* ev   = (const float*)d_in[1];
  const int*   eidx = (const int*)d_in[2];
  const float* cg   = (const float*)d_in[3];
  const float* tpw  = (const float*)d_in[4];
  const float* wlin = (const float*)d_in[5];
  const float* blin = (const float*)d_in[6];
  float* out = (float*)d_out;

  int NA = in_sizes[0] / 1024;
  int NE = in_sizes[1] / 3;
  f16* F   = (f16*)d_ws;
  f16* CGd = (f16*)((char*)d_ws + (size_t)64 * 64 * NKPAD * 2);

  zero_ws<<<256, 256, 0, stream>>>((uint4*)F);
  compute_F<<<NKK, 256, 0, stream>>>(tpw, wlin, F);
  compute_CGd<<<NKPAD, 256, 0, stream>>>(cg, CGd);
  init_out<<<(NA * 64 + 255) / 256, 256, 0, stream>>>(out, blin, NA * 64);
  edge_kernel<<<(NE + EPB - 1) / EPB, THREADS, 0, stream>>>(nf, ev, eidx, CGd, F, out, NE);
}

// Round 5
// 941.430 us; speedup vs baseline: 1.1966x; 1.1966x over previous
//
#include <hip/hip_runtime.h>

// SimpleMACELayer on gfx950 — round 5: round-4 prefetch structure, spill-free.
//
//   F[h][o2][kk]   = sum_o tpw[p(kk)][h][o] * W_lin[o2][o*16 + kg(kk)]  (f16, kk pad 128, ws)
//   CGd[kk][i][j]  = masked-dense Gaunt slice (f16, ws)
//   A_e[kk][i]     = CGd[kk]·Y_e          (MFMA 16x16x16, built during G2(hg=3) phase)
//   U[e][h][kk]    = A_e·src_e            (GEMM-1)
//   out[dst,:]    += U·F                  (GEMM-2, F prefetched into pf[4][4] regs a phase early)
//
// Round-4 post-mortem: __launch_bounds__(256,4) capped VGPR at 128; pf(64)+Sf(32)+acc(16)
// spilled to scratch (WRITE_SIZE 25->300MB, FETCH 218->764MB) => regression. Round-3's true
// bottleneck: 16 F-loads/phase serialized at L2 latency (56 VGPR). Fix: (256,3) => 168 VGPR
// cap, prefetch stays in registers; 3 blocks/CU instead of 4.

#define NKK 99
#define NKPAD 128
#define EPB 16
#define THREADS 256
#define SA_ESTR 516   // [e][kk32][i16] f16 (+ XOR i-block swizzle)
#define SU_HSTR 40    // [e][h'16][kk32] f16
#define SU_ESTR 648

typedef _Float16 f16;
typedef f16 f16x4 __attribute__((ext_vector_type(4)));
typedef f16 f16x8 __attribute__((ext_vector_type(8)));
typedef float f32x4 __attribute__((ext_vector_type(4)));

__device__ __constant__ short PK_P[NKK] = {
  0, 1,1,1, 2,2,2,2,2, 3,3,3,3,3,3,3, 4,4,4, 5, 6,6,6,6,6, 7,7,7,
  8,8,8,8,8,8,8, 9,9,9,9,9, 10,10,10,10,10, 11,11,11, 12,12,12,12,12,12,12,
  13, 14,14,14,14,14, 15,15,15, 16,16,16,16,16,16,16, 17,17,17,17,17,17,17,
  18,18,18,18,18, 19,19,19, 20,20,20,20,20,20,20, 21, 22,22,22,22,22};
__device__ __constant__ short KK_L1[NKK] = {
  0, 0,0,0, 0,0,0,0,0, 0,0,0,0,0,0,0, 1,1,1, 1, 1,1,1,1,1, 1,1,1,
  1,1,1,1,1,1,1, 1,1,1,1,1, 2,2,2,2,2, 2,2,2, 2,2,2,2,2,2,2,
  2, 2,2,2,2,2, 2,2,2, 2,2,2,2,2,2,2, 3,3,3,3,3,3,3,
  3,3,3,3,3, 3,3,3, 3,3,3,3,3,3,3, 3, 3,3,3,3,3};
__device__ __constant__ short KK_L2[NKK] = {
  0, 1,1,1, 2,2,2,2,2, 3,3,3,3,3,3,3, 0,0,0, 1, 1,1,1,1,1, 2,2,2,
  2,2,2,2,2,2,2, 3,3,3,3,3, 0,0,0,0,0, 1,1,1, 1,1,1,1,1,1,1,
  2, 2,2,2,2,2, 3,3,3, 3,3,3,3,3,3,3, 0,0,0,0,0,0,0,
  1,1,1,1,1, 2,2,2, 2,2,2,2,2,2,2, 3, 3,3,3,3,3};
__device__ __constant__ short KK_KG[NKK] = {
  0, 1,2,3, 4,5,6,7,8, 9,10,11,12,13,14,15, 1,2,3, 0, 4,5,6,7,8, 1,2,3,
  9,10,11,12,13,14,15, 4,5,6,7,8, 4,5,6,7,8, 1,2,3, 9,10,11,12,13,14,15,
  0, 4,5,6,7,8, 1,2,3, 9,10,11,12,13,14,15, 9,10,11,12,13,14,15,
  4,5,6,7,8, 1,2,3, 9,10,11,12,13,14,15, 0, 4,5,6,7,8};

__global__ void zero_ws(uint4* __restrict__ F) {
  F[blockIdx.x * 256 + threadIdx.x] = uint4{0, 0, 0, 0};
}

__global__ __launch_bounds__(256) void compute_F(const float* __restrict__ tpw,
                                                 const float* __restrict__ wlin,
                                                 f16* __restrict__ F) {
  int kk = blockIdx.x;
  int p  = PK_P[kk];
  int c3 = KK_KG[kk];

  __shared__ float wl[64][65];
  int tid = threadIdx.x;
  for (int idx = tid; idx < 64 * 64; idx += 256) {
    int o2 = idx >> 6, o = idx & 63;
    wl[o2][o] = wlin[o2 * 1024 + o * 16 + c3];
  }
  __syncthreads();

  int h = tid & 63, og = tid >> 6;
  float acc[16];
#pragma unroll
  for (int m = 0; m < 16; ++m) acc[m] = 0.f;
  const float* tw = tpw + (p * 64 + h) * 64;
  for (int o = 0; o < 64; ++o) {
    float w = tw[o];
#pragma unroll
    for (int m = 0; m < 16; ++m) acc[m] += w * wl[og * 16 + m][o];
  }
#pragma unroll
  for (int m = 0; m < 16; ++m)
    F[(size_t)(h * 64 + og * 16 + m) * NKPAD + kk] = (f16)acc[m];
}

__global__ void compute_CGd(const float* __restrict__ cg, f16* __restrict__ CGd) {
  int kk = blockIdx.x;
  int i = threadIdx.x >> 4, j = threadIdx.x & 15;
  f16 v = (f16)0.f;
  if (kk < NKK) {
    int l1 = KK_L1[kk], l2 = KK_L2[kk], kg = KK_KG[kk];
    int b1 = l1 * l1, b2 = l2 * l2;
    if (i >= b1 && i < b1 + 2 * l1 + 1 && j >= b2 && j < b2 + 2 * l2 + 1)
      v = (f16)cg[(i * 16 + j) * 16 + kg];
  }
  CGd[kk * 256 + i * 16 + j] = v;
}

__global__ void init_out(float* __restrict__ out, const float* __restrict__ b, int n) {
  int i = blockIdx.x * 256 + threadIdx.x;
  if (i < n) out[i] = b[i & 63];
}

// ---------------- main edge kernel (VGPR cap 168 via min-3-waves/EU: no spills)
__global__ __launch_bounds__(THREADS, 3) void edge_kernel(
    const float* __restrict__ nf, const float* __restrict__ ev,
    const int* __restrict__ eidx, const f16* __restrict__ CGd,
    const f16* __restrict__ F, float* __restrict__ out, int NE) {

  __shared__ f16 sYh[EPB * 16];
  __shared__ int sSrcA[EPB];
  __shared__ int sDst[EPB];
  __shared__ f16 sA[EPB * SA_ESTR];   // 16.5KB ; reused as fp32 red
  __shared__ f16 sU[EPB * SU_ESTR];   // 20.7KB

  int tid = threadIdx.x;
  int wave = tid >> 6, lane = tid & 63;
  int lm = lane & 15, lq = lane >> 4;

  // --- phase 0: edge meta + spherical harmonics (f16)
  if (tid < EPB) {
    int eg = blockIdx.x * EPB + tid;
    int sa = 0, da = -1;
    float x = 0.f, y = 0.f, z = 0.f;
    if (eg < NE) {
      sa = eidx[eg];
      da = eidx[NE + eg];
      x = ev[3 * eg + 0]; y = ev[3 * eg + 1]; z = ev[3 * eg + 2];
    }
    sSrcA[tid] = sa;
    sDst[tid] = da;
    float x2 = x * x, y2 = y * y, z2 = z * z;
    float Y[16];
    Y[0]  = 0.28209479177387814f;
    Y[1]  = 0.4886025119029199f * y;
    Y[2]  = 0.4886025119029199f * z;
    Y[3]  = 0.4886025119029199f * x;
    Y[4]  = 1.0925484305920792f * x * y;
    Y[5]  = 1.0925484305920792f * y * z;
    Y[6]  = 0.31539156525252005f * (3.0f * z2 - 1.0f);
    Y[7]  = 1.0925484305920792f * x * z;
    Y[8]  = 0.5462742152960396f * (x2 - y2);
    Y[9]  = 0.5900435899266435f * y * (3.0f * x2 - y2);
    Y[10] = 2.890611442640554f * x * y * z;
    Y[11] = 0.4570457994644658f * y * (5.0f * z2 - 1.0f);
    Y[12] = 0.3731763325901154f * z * (5.0f * z2 - 3.0f);
    Y[13] = 0.4570457994644658f * x * (5.0f * z2 - 1.0f);
    Y[14] = 1.445305721320277f  * z * (x2 - y2);
    Y[15] = 0.5900435899266435f * x * (x2 - 3.0f * y2);
#pragma unroll
    for (int j = 0; j < 16; ++j) sYh[tid * 16 + j] = (f16)Y[j];
  }
  __syncthreads();

  // --- phase 1: Sf gather + bY + A-build(kg=0) + pf(0,0) prefetch
  f16x4 Sf[4][4];
  int ebase = wave * 4;
#pragma unroll
  for (int ei = 0; ei < 4; ++ei) {
    const float4* src4 = (const float4*)nf + (size_t)sSrcA[ebase + ei] * 256;
#pragma unroll
    for (int hg = 0; hg < 4; ++hg) {
      float4 v = src4[(hg * 16 + lm) * 4 + lq];
      Sf[ei][hg] = f16x4{(f16)v.x, (f16)v.y, (f16)v.z, (f16)v.w};
    }
  }

  f16x4 bY = *(const f16x4*)&sYh[lm * 16 + lq * 4];

  // per-lane bases
  const f16* Fbase = F + (size_t)lm * NKPAD + lq * 8;  // + h*64*NKPAD + ot*16*NKPAD + kg*32
  int sAw = lm * SA_ESTR;
  int sUw = lm * SU_HSTR;

  // A-build for kg=0
#pragma unroll
  for (int tl = 0; tl < 8; ++tl) {
    int t = wave * 8 + tl;
    f16x4 aCG = *(const f16x4*)&CGd[(size_t)t * 256 + lm * 16 + lq * 4];
    f32x4 d = __builtin_amdgcn_mfma_f32_16x16x16f16(aCG, bY, f32x4{0.f, 0.f, 0.f, 0.f}, 0, 0, 0);
    f16x4 dh = {(f16)d[0], (f16)d[1], (f16)d[2], (f16)d[3]};
    int loc = lq ^ ((t >> 2) & 3);
    *(f16x4*)&sA[sAw + t * 16 + loc * 4] = dh;
  }

  // prefetch F fragments for phase (kg=0, hg=0)
  f16x8 pf[4][4];
#pragma unroll
  for (int hi = 0; hi < 4; ++hi) {
    int h = wave + 4 * hi;
#pragma unroll
    for (int ot = 0; ot < 4; ++ot)
      pf[hi][ot] = *(const f16x8*)(Fbase + (size_t)(h * 64 + ot * 16) * NKPAD);
  }

  f32x4 acc[4];
#pragma unroll
  for (int ot = 0; ot < 4; ++ot) acc[ot] = f32x4{0.f, 0.f, 0.f, 0.f};

  int swz = (lm >> 2) & 3;

  __syncthreads();

  for (int kg = 0; kg < 4; ++kg) {
#pragma unroll
    for (int hg = 0; hg < 4; ++hg) {
      // ---- G1 phase: U[e][h'=lm][kk32] writes
#pragma unroll
      for (int ei = 0; ei < 4; ++ei) {
        int e = ebase + ei;
        f16x4 bS = Sf[ei][hg];
#pragma unroll
        for (int mt = 0; mt < 2; ++mt) {
          f16x4 aA = *(const f16x4*)&sA[e * SA_ESTR + (mt * 16 + lm) * 16 + ((lq ^ swz) << 2)];
          f32x4 d = __builtin_amdgcn_mfma_f32_16x16x16f16(aA, bS, f32x4{0.f, 0.f, 0.f, 0.f}, 0, 0, 0);
          f16x4 dh = {(f16)d[0], (f16)d[1], (f16)d[2], (f16)d[3]};
          *(f16x4*)&sU[e * SU_ESTR + sUw + mt * 16 + lq * 4] = dh;
        }
      }
      __syncthreads();

      // ---- G2 phase: acc += U*F from pf regs; refill pf with next phase's F after last use
      int tn = kg * 4 + hg + 1;
      int kgn = (tn >> 2) & 3, hgn = tn & 3;
#pragma unroll
      for (int hi = 0; hi < 4; ++hi) {
        int hl = wave + 4 * hi;
        f16x8 a0 = *(const f16x8*)&sU[lm * SU_ESTR + hl * SU_HSTR + lq * 8];
        int hn = hgn * 16 + wave + 4 * hi;
#pragma unroll
        for (int ot = 0; ot < 4; ++ot) {
          acc[ot] = __builtin_amdgcn_mfma_f32_16x16x32_f16(a0, pf[hi][ot], acc[ot], 0, 0, 0);
          pf[hi][ot] = *(const f16x8*)(Fbase + (size_t)(hn * 64 + ot * 16) * NKPAD + kgn * 32);
        }
      }

      if (hg == 3) {
        // A-build for next kg (sA free: last read was G1 of this kg, pre-mid-barrier)
        int kga = (kg + 1) & 3;
#pragma unroll
        for (int tl = 0; tl < 8; ++tl) {
          int t = wave * 8 + tl;
          f16x4 aCG = *(const f16x4*)&CGd[(size_t)(kga * 32 + t) * 256 + lm * 16 + lq * 4];
          f32x4 d = __builtin_amdgcn_mfma_f32_16x16x16f16(aCG, bY, f32x4{0.f, 0.f, 0.f, 0.f}, 0, 0, 0);
          f16x4 dh = {(f16)d[0], (f16)d[1], (f16)d[2], (f16)d[3]};
          int loc = lq ^ ((t >> 2) & 3);
          *(f16x4*)&sA[sAw + t * 16 + loc * 4] = dh;
        }
      }
      __syncthreads();
    }
  }

  // --- cross-wave reduction: red[e][o2][wave] + atomic scatter
  float* red = (float*)sA;
#pragma unroll
  for (int ot = 0; ot < 4; ++ot) {
#pragma unroll
    for (int r = 0; r < 4; ++r) {
      int e = lq * 4 + r;
      int o2 = ot * 16 + lm;
      red[(e * 64 + o2) * 4 + wave] = acc[ot][r];
    }
  }
  __syncthreads();

#pragma unroll
  for (int rep = 0; rep < 4; ++rep) {
    int idx = tid + rep * 256;
    float4 v = *(const float4*)&red[idx * 4];
    float s = v.x + v.y + v.z + v.w;
    int e = idx >> 6, o2 = idx & 63;
    int da = sDst[e];
    if (da >= 0) unsafeAtomicAdd(out + (size_t)da * 64 + o2, s);
  }
}

extern "C" void kernel_launch(void* const* d_in, const int* in_sizes, int n_in,
                              void* d_out, int out_size, void* d_ws, size_t ws_size,
                              hipStream_t stream) {
  const float* nf   = (const float*)d_in[0];
  const float* ev   = (const float*)d_in[1];
  const int*   eidx = (const int*)d_in[2];
  const float* cg   = (const float*)d_in[3];
  const float* tpw  = (const float*)d_in[4];
  const float* wlin = (const float*)d_in[5];
  const float* blin = (const float*)d_in[6];
  float* out = (float*)d_out;

  int NA = in_sizes[0] / 1024;
  int NE = in_sizes[1] / 3;
  f16* F   = (f16*)d_ws;
  f16* CGd = (f16*)((char*)d_ws + (size_t)64 * 64 * NKPAD * 2);

  zero_ws<<<256, 256, 0, stream>>>((uint4*)F);
  compute_F<<<NKK, 256, 0, stream>>>(tpw, wlin, F);
  compute_CGd<<<NKPAD, 256, 0, stream>>>(cg, CGd);
  init_out<<<(NA * 64 + 255) / 256, 256, 0, stream>>>(out, blin, NA * 64);
  edge_kernel<<<(NE + EPB - 1) / EPB, THREADS, 0, stream>>>(nf, ev, eidx, CGd, F, out, NE);
}